// Round 16
// baseline (100.440 us; speedup 1.0000x reference)
//
#include <hip/hip_runtime.h>
#include <hip/hip_bf16.h>
#include <math.h>

#define BB 16
#define NTOK 1024
#define CDIM 256
#define HEADS 8
#define HD 32
#define LOG2E 1.4426950408889634f
#define PSHIFT 18.0f

typedef __attribute__((ext_vector_type(8))) _Float16 half8;
typedef __attribute__((ext_vector_type(8))) unsigned short u16x8;
typedef __attribute__((ext_vector_type(4))) unsigned int u32x4;
typedef __attribute__((ext_vector_type(4))) float f32x4;

__device__ __forceinline__ unsigned short f2h(float f) {
  _Float16 h = (_Float16)f;
  return __builtin_bit_cast(unsigned short, h);
}
__device__ __forceinline__ half8 ldh8(const unsigned short* p) {
  return *reinterpret_cast<const half8*>(p);
}
__device__ __forceinline__ void gl_lds16(const unsigned short* g,
                                         unsigned short* l) {
  __builtin_amdgcn_global_load_lds(
      (const __attribute__((address_space(1))) unsigned int*)g,
      (__attribute__((address_space(3))) unsigned int*)l, 16, 0, 0);
}

// ---------------------------------------------------------------------------
__global__ __launch_bounds__(256) void cvt_x(const float* __restrict__ X,
                                             unsigned short* __restrict__ x16) {
  size_t base = ((size_t)blockIdx.x * 256 + threadIdx.x) * 8;
  float4 a = *(const float4*)(X + base);
  float4 b = *(const float4*)(X + base + 4);
  u16x8 o = {f2h(a.x), f2h(a.y), f2h(a.z), f2h(a.w),
             f2h(b.x), f2h(b.y), f2h(b.z), f2h(b.w)};
  *(u16x8*)(x16 + base) = o;
}

// Transpose weights into (N,K) fp16.
__global__ __launch_bounds__(256) void cvt_w(
    const float* __restrict__ Wq, const float* __restrict__ Wkv,
    const float* __restrict__ Wp, unsigned short* __restrict__ wt16,
    unsigned short* __restrict__ wp16) {
  int idx = blockIdx.x * 256 + threadIdx.x;  // 0 .. 262143
  float val; size_t dst; bool isp = false;
  if (idx < 65536) {
    int k = idx >> 8, n = idx & 255;
    val = Wq[idx]; dst = (size_t)n * 256 + k;
  } else if (idx < 196608) {
    int i2 = idx - 65536;
    int k = i2 >> 9, n2 = i2 & 511;
    val = Wkv[i2]; dst = (size_t)(256 + n2) * 256 + k;
  } else {
    int i3 = idx - 196608;
    int k = i3 >> 8, n = i3 & 255;
    val = Wp[i3]; dst = (size_t)n * 256 + k; isp = true;
  }
  unsigned short h = f2h(val);
  if (isp) wp16[dst] = h; else wt16[dst] = h;
}

// ---------------------------------------------------------------------------
__global__ __launch_bounds__(256) void bias_kernel(
    const float* __restrict__ affine, const float* __restrict__ atab,
    float* __restrict__ bias) {
  int idx = blockIdx.x * 256 + threadIdx.x;
  if (idx >= BB * NTOK) return;
  int b = idx >> 10, n = idx & (NTOK - 1);
  float cx = (float)(n & 31);
  float cy = (float)(n >> 5);
  const float* A = affine + b * 6;
  float egx = fmaf(A[0], 16.f, fmaf(A[1], 16.f, A[2]));
  float egy = fmaf(A[3], 16.f, fmaf(A[4], 16.f, A[5]));
  float ang = atan2f(cy - egy, cx - egx);
  float t = (ang + 3.14159265358979323846f) *
            (1.f / (2.f * 3.14159265358979323846f)) * 4.f;
  int bin = (int)t;
  bin = bin < 0 ? 0 : (bin > 4 ? 4 : bin);
  for (int h = 0; h < HEADS; ++h) {
    float a = atab[bin * HEADS + h];
    float s = 1.f / (1.f + __expf(-a));
    bias[((size_t)b * HEADS + h) * NTOK + n] = 1.f + s;
  }
}

// ---------------------------------------------------------------------------
// maskF: mask*log2e - PSHIFT in EVEN/ODD-interleaved MFMA C-fragment order:
//  key k -> slab kt*4 + hf*2 + (k&1), ins = q*16 + (k&31)>>1.
// ---------------------------------------------------------------------------
__global__ __launch_bounds__(256) void mask_prepF(const float* __restrict__ m,
                                                  float* __restrict__ mF) {
  int idx = blockIdx.x * 256 + threadIdx.x;  // thread per float4; 1,048,576
  int b4 = idx >> 18;
  int rem = idx & 262143;
  int q = rem >> 8;
  int k = (rem & 255) * 4;
  float4 v = *(const float4*)(m + ((size_t)b4 * NTOK + q) * NTOK + k);
  float4 o = {fmaf(v.x, LOG2E, -PSHIFT), fmaf(v.y, LOG2E, -PSHIFT),
              fmaf(v.z, LOG2E, -PSHIFT), fmaf(v.w, LOG2E, -PSHIFT)};
  int kt = k >> 6, hf = (k >> 5) & 1, a = (k & 31) >> 2;
  size_t base = ((size_t)((b4 * 16 + kt) * 4 + hf * 2)) * 16384 + q * 16 + a * 2;
  float2 e = {o.x, o.z};   // even keys -> fp=0 slab
  float2 d = {o.y, o.w};   // odd keys  -> fp=1 slab
  *(float2*)(mF + base) = e;
  *(float2*)(mF + base + 16384) = d;
}

// ---------------------------------------------------------------------------
// QKV projection: round-12 structure (fp16 MFMA, 128x128/BK=32,
// 2-buffer __syncthreads dbuf, u16 LDS-bounce epilogue).
// ---------------------------------------------------------------------------
__global__ __launch_bounds__(512, 4) void gemm_qkv16(
    const unsigned short* __restrict__ x16, const unsigned short* __restrict__ wt16,
    const float* __restrict__ bq, const float* __restrict__ bkv,
    const float* __restrict__ bias, unsigned short* __restrict__ q16,
    unsigned short* __restrict__ k16, unsigned short* __restrict__ vt16) {
  __shared__ __align__(16) unsigned short SM[16384];  // 32 KB multi-use
  unsigned short* Xs = SM;            // [2][4096]
  unsigned short* Ws = SM + 8192;     // [2][4096]
  int tid = threadIdx.x;
  int w = tid >> 6, l = tid & 63;
  int row16 = l & 15, grp = l >> 4;
  int bid = blockIdx.x;
  int xcd = bid & 7, local = bid >> 3;        // 0..95
  int jb = local % 6, mb = xcd * 16 + local / 6;
  int j0 = jb * 128, m0 = mb * 128;
  int wm = w >> 1, wn = w & 1;

  auto stg = [&](int nb, int kt) {  // 1KB chunk per operand per wave
    int k0s = kt * 32;
    int row = w * 16 + (l >> 2);
    int ge = (((l & 3) * 16) ^ ((row & 3) << 4)) >> 1;
    gl_lds16(x16 + (size_t)(m0 + row) * 256 + k0s + ge, Xs + nb * 4096 + w * 512);
    gl_lds16(wt16 + (size_t)(j0 + row) * 256 + k0s + ge, Ws + nb * 4096 + w * 512);
  };
  auto off16 = [&](int row, int g) {
    return row * 32 + ((((g * 16) ^ ((row & 3) << 4))) >> 1);
  };

  stg(0, 0);
  __syncthreads();

  f32x4 acc[2][4];
#pragma unroll
  for (int i = 0; i < 2; ++i)
#pragma unroll
    for (int c = 0; c < 4; ++c) acc[i][c] = (f32x4){0.f, 0.f, 0.f, 0.f};

  for (int kt = 0; kt < 8; ++kt) {
    int cur = kt & 1;
    if (kt < 7) stg(cur ^ 1, kt + 1);
    half8 a0 = ldh8(Xs + cur * 4096 + off16(wm * 32 + row16, grp));
    half8 a1 = ldh8(Xs + cur * 4096 + off16(wm * 32 + 16 + row16, grp));
#pragma unroll
    for (int c = 0; c < 4; ++c) {
      half8 bh = ldh8(Ws + cur * 4096 + off16(wn * 64 + c * 16 + row16, grp));
      acc[0][c] = __builtin_amdgcn_mfma_f32_16x16x32_f16(a0, bh, acc[0][c], 0, 0, 0);
      acc[1][c] = __builtin_amdgcn_mfma_f32_16x16x32_f16(a1, bh, acc[1][c], 0, 0, 0);
    }
    __syncthreads();
  }

  // epilogue: bounce through SM as u16 [64][136], two 64-row halves
  const float scaleq = 0.17677669529663687f * LOG2E;
  int half_mine = wm >> 1;
  for (int half = 0; half < 2; ++half) {
    if (half_mine == half) {
#pragma unroll
      for (int i = 0; i < 2; ++i) {
#pragma unroll
        for (int c = 0; c < 4; ++c) {
          int col = wn * 64 + c * 16 + row16;
          int jg = j0 + col;
#pragma unroll
          for (int r = 0; r < 4; ++r) {
            int rowl = (wm & 1) * 32 + i * 16 + grp * 4 + r;
            int m = m0 + half * 64 + rowl;
            int b = m >> 10, n = m & (NTOK - 1);
            float val = acc[i][c][r];
            unsigned short o;
            if (jb < 2)
              o = f2h((val + bq[jg]) * scaleq *
                      bias[((size_t)b * HEADS + (jg >> 5)) * NTOK + n]);
            else
              o = f2h(val + bkv[jg - CDIM]);
            SM[rowl * 136 + col] = o;
          }
        }
      }
    }
    __syncthreads();
    if (jb < 4) {
#pragma unroll
      for (int it = 0; it < 2; ++it) {
        int lin = it * 512 + tid;
        int rowb = lin >> 4, oct = lin & 15;
        u16x8 v = *(const u16x8*)&SM[rowb * 136 + oct * 8];
        int m = m0 + half * 64 + rowb;
        int b = m >> 10, n = m & (NTOK - 1);
        int jg = j0 + oct * 8;
        unsigned short* dst; int h, d;
        if (jb < 2) { h = jg >> 5; d = jg & 31; dst = q16; }
        else { int c2 = jg - CDIM; h = c2 >> 5; d = c2 & 31; dst = k16; }
        *(u16x8*)(dst + (((size_t)b * HEADS + h) * NTOK + n) * HD + d) = v;
      }
    } else {
#pragma unroll
      for (int it = 0; it < 2; ++it) {
        int lin = it * 512 + tid;
        int noct = lin >> 7, jl = lin & 127;
        u16x8 v;
#pragma unroll
        for (int e = 0; e < 8; ++e) v[e] = SM[(noct * 8 + e) * 136 + jl];
        int c3 = j0 + jl - 2 * CDIM;
        int h = c3 >> 5, d = c3 & 31;
        int n0 = m0 + half * 64 + noct * 8;
        int b = n0 >> 10, nn = n0 & (NTOK - 1);
        *(u16x8*)(vt16 + (((size_t)b * HEADS + h) * HD + d) * NTOK + nn) = v;
      }
    }
    __syncthreads();
  }
}

// ---------------------------------------------------------------------------
// Flash attention (R15 structure) with XCD-pinned q-tiles: qt = bid&7, so
// each XCD's mask working set = 4 slabs x 512 KB = 2 MB -> L2-resident
// (the 512 MB mask stream moves from L3 to L2).
// ---------------------------------------------------------------------------
__global__ __launch_bounds__(512, 8) void attn16(
    const unsigned short* __restrict__ q16, const unsigned short* __restrict__ k16,
    const unsigned short* __restrict__ vt16, const float* __restrict__ maskF,
    unsigned short* __restrict__ ao16) {
  __shared__ __align__(16) unsigned short KT[2][2048];  // fp16 [64k][32d] swz
  __shared__ __align__(16) unsigned short VT[2][2048];  // fp16 [32d][64k] swz

  int tid = threadIdx.x;
  int w = tid >> 6, l = tid & 63;
  int row16 = l & 15, grp = l >> 4;
  int bid = blockIdx.x;
  // XCD-pinned q-tile: dispatch round-robins bid%8 across XCDs.
  int qt = bid & 7, h = (bid >> 3) & 7, b = bid >> 6;
  int q0 = qt * 128;
  int bh = b * HEADS + h;

  // Q as B-operand: col=q=row16, k-dim=d
  size_t qidx = (((size_t)bh * NTOK) + q0 + w * 16 + row16) * HD + grp * 8;
  half8 bq16 = ldh8(q16 + qidx);

  const float* mFb = maskF + (size_t)(b & 3) * 64 * 16384 +
                     (q0 + w * 16 + row16) * 16 + grp * 4;

  f32x4 accd[2];
  accd[0] = (f32x4){0.f, 0.f, 0.f, 0.f};
  accd[1] = (f32x4){0.f, 0.f, 0.f, 0.f};
  float lsum = 0.f;

  auto stage = [&](int nbuf, int kt2) {  // 8 x 1KB chunks, 1 per wave
    int k0n = kt2 * 64;
    if (w < 4) {  // K: LDS row r holds key perm(r); source remapped
      int r = w * 16 + (l >> 2);                       // LDS row
      int key = ((r >> 5) << 5) + 2 * (r & 15) + ((r >> 4) & 1);
      int gd = (((l & 3) * 16) ^ ((r & 3) << 4)) >> 1;
      gl_lds16(k16 + (((size_t)bh * NTOK) + k0n + key) * HD + gd,
               &KT[nbuf][w * 16 * 32]);
    } else {      // V^T: [32d][64k] fp16, 8-slot XOR
      int sub = w - 4;
      int dl = sub * 8 + (l >> 3);
      int gk = (((l & 7) * 16) ^ ((dl & 7) << 4)) >> 1;
      gl_lds16(vt16 + ((size_t)bh * HD + dl) * NTOK + k0n + gk,
               &VT[nbuf][sub * 8 * 64]);
    }
  };

  stage(0, 0);
  __syncthreads();

  for (int kt = 0; kt < 16; ++kt) {
    int cur = kt & 1;
    if (kt < 15) stage(cur ^ 1, kt + 1);

    // mask C-fragments for this tile: 4 coalesced f32x4 loads (L2-hot)
    f32x4 mC[4];
#pragma unroll
    for (int f = 0; f < 4; ++f)
      mC[f] = *(const f32x4*)(mFb + (size_t)(kt * 4 + f) * 16384);

#pragma unroll
    for (int hf = 0; hf < 2; ++hf) {
      f32x4 s[2];
#pragma unroll
      for (int fp = 0; fp < 2; ++fp) {
        int f = hf * 2 + fp;
        int kl = f * 16 + row16;  // consecutive LDS rows (R12 bank pattern)
        int cb = (grp * 16) ^ ((kl & 3) << 4);
        half8 kf = ldh8(&KT[cur][kl * 32 + (cb >> 1)]);
        // lane (q=row16, grp), reg r gets key hf*32 + 8*grp + 2r + fp
        s[fp] = __builtin_amdgcn_mfma_f32_16x16x32_f16(kf, bq16,
                                                       mC[f], 0, 0, 0);
      }
      f32x4 e0, e1;
#pragma unroll
      for (int r = 0; r < 4; ++r) {
        e0[r] = __builtin_amdgcn_exp2f(s[0][r]);
        e1[r] = __builtin_amdgcn_exp2f(s[1][r]);
      }
      lsum += ((e0[0] + e1[0]) + (e0[1] + e1[1])) +
              ((e0[2] + e1[2]) + (e0[3] + e1[3]));
      u32x4 pk;
#pragma unroll
      for (int r = 0; r < 4; ++r)
        pk[r] = __builtin_bit_cast(unsigned,
                                   __builtin_amdgcn_cvt_pkrtz(e0[r], e1[r]));
      half8 pa = __builtin_bit_cast(half8, pk);  // keys 8grp..8grp+7 (hf half)
#pragma unroll
      for (int df = 0; df < 2; ++df) {
        int dl = df * 16 + row16;
        int cb = (hf * 64 + grp * 16) ^ ((dl & 7) << 4);
        half8 v = ldh8(&VT[cur][dl * 64 + (cb >> 1)]);
        accd[df] = __builtin_amdgcn_mfma_f32_16x16x32_f16(pa, v, accd[df], 0, 0, 0);
      }
    }
    __syncthreads();
  }

  // row-sum: reduce across the 4 grp slices for fixed row16
  lsum += __shfl_xor(lsum, 16);
  lsum += __shfl_xor(lsum, 32);
#pragma unroll
  for (int r = 0; r < 4; ++r) {
    float lr = __shfl(lsum, grp * 4 + r, 16);
    float inv = 1.f / lr;
    int qrow = q0 + w * 16 + grp * 4 + r;
    size_t obase = ((size_t)b * NTOK + qrow) * CDIM + h * HD;
    ao16[obase + row16] = f2h(accd[0][r] * inv);
    ao16[obase + 16 + row16] = f2h(accd[1][r] * inv);
  }
}

// ---------------------------------------------------------------------------
// Output projection: round-12 structure.
// ---------------------------------------------------------------------------
__global__ __launch_bounds__(512, 4) void gemm_out16(
    const unsigned short* __restrict__ a16, const unsigned short* __restrict__ wp16,
    const float* __restrict__ bp, float* __restrict__ out) {
  __shared__ __align__(16) unsigned short SM[16384];
  unsigned short* Xs = SM;
  unsigned short* Ws = SM + 8192;
  int tid = threadIdx.x;
  int w = tid >> 6, l = tid & 63;
  int row16 = l & 15, grp = l >> 4;
  int bid = blockIdx.x;
  int xcd = bid & 7, local = bid >> 3;
  int jb = local & 1, mb = xcd * 16 + (local >> 1);
  int j0 = jb * 128, m0 = mb * 128;
  int wm = w >> 1, wn = w & 1;

  auto stg = [&](int nb, int kt) {
    int k0s = kt * 32;
    int row = w * 16 + (l >> 2);
    int ge = (((l & 3) * 16) ^ ((row & 3) << 4)) >> 1;
    gl_lds16(a16 + (size_t)(m0 + row) * 256 + k0s + ge, Xs + nb * 4096 + w * 512);
    gl_lds16(wp16 + (size_t)(j0 + row) * 256 + k0s + ge, Ws + nb * 4096 + w * 512);
  };
  auto off16 = [&](int row, int g) {
    return row * 32 + ((((g * 16) ^ ((row & 3) << 4))) >> 1);
  };

  stg(0, 0);
  __syncthreads();

  f32x4 acc[2][4];
#pragma unroll
  for (int i = 0; i < 2; ++i)
#pragma unroll
    for (int c = 0; c < 4; ++c) acc[i][c] = (f32x4){0.f, 0.f, 0.f, 0.f};

  for (int kt = 0; kt < 8; ++kt) {
    int cur = kt & 1;
    if (kt < 7) stg(cur ^ 1, kt + 1);
    half8 a0 = ldh8(Xs + cur * 4096 + off16(wm * 32 + row16, grp));
    half8 a1 = ldh8(Xs + cur * 4096 + off16(wm * 32 + 16 + row16, grp));
#pragma unroll
    for (int c = 0; c < 4; ++c) {
      half8 bh = ldh8(Ws + cur * 4096 + off16(wn * 64 + c * 16 + row16, grp));
      acc[0][c] = __builtin_amdgcn_mfma_f32_16x16x32_f16(a0, bh, acc[0][c], 0, 0, 0);
      acc[1][c] = __builtin_amdgcn_mfma_f32_16x16x32_f16(a1, bh, acc[1][c], 0, 0, 0);
    }
    __syncthreads();
  }

#pragma unroll
  for (int i = 0; i < 2; ++i) {
    int ng = m0 + wm * 32 + i * 16 + grp * 4;
#pragma unroll
    for (int c = 0; c < 4; ++c) {
      int jg = j0 + wn * 64 + c * 16 + row16;
      float bias = bp[jg];
#pragma unroll
      for (int r = 0; r < 4; ++r) {
        out[(size_t)(ng + r) * CDIM + jg] = acc[i][c][r] + bias;
      }
    }
  }
}

// ---------------------------------------------------------------------------
extern "C" void kernel_launch(void* const* d_in, const int* in_sizes, int n_in,
                              void* d_out, int out_size, void* d_ws,
                              size_t ws_size, hipStream_t stream) {
  const float* x = (const float*)d_in[0];
  const float* mask = (const float*)d_in[1];
  const float* affine = (const float*)d_in[2];
  const float* Wq = (const float*)d_in[3];
  const float* bq = (const float*)d_in[4];
  const float* Wkv = (const float*)d_in[5];
  const float* bkv = (const float*)d_in[6];
  const float* Wp = (const float*)d_in[7];
  const float* bp = (const float*)d_in[8];
  const float* atab = (const float*)d_in[9];
  float* out = (float*)d_out;

  const size_t bhnd = (size_t)BB * HEADS * NTOK * HD;  // 4,194,304
  unsigned short* q16 = (unsigned short*)d_ws;
  unsigned short* k16 = q16 + bhnd;
  unsigned short* vt16 = k16 + bhnd;
  unsigned short* x16 = vt16 + bhnd;     // aliased as ao16 after qkv
  unsigned short* wt16 = x16 + bhnd;     // 768*256
  unsigned short* wp16 = wt16 + 768 * 256;
  float* bias = (float*)(wp16 + 256 * 256);
  float* maskF = bias + (size_t)BB * HEADS * NTOK;

  cvt_x<<<2048, 256, 0, stream>>>(x, x16);
  cvt_w<<<1024, 256, 0, stream>>>(Wq, Wkv, Wp, wt16, wp16);
  bias_kernel<<<64, 256, 0, stream>>>(affine, atab, bias);
  mask_prepF<<<4096, 256, 0, stream>>>(mask, maskF);
  gemm_qkv16<<<768, 512, 0, stream>>>(x16, wt16, bq, bkv, bias, q16, k16, vt16);
  attn16<<<1024, 512, 0, stream>>>(q16, k16, vt16, maskF, x16);
  gemm_out16<<<256, 512, 0, stream>>>(x16, wp16, bp, out);
}

// Round 17
// 95.959 us; speedup vs baseline: 1.0467x; 1.0467x over previous
//
#include <hip/hip_runtime.h>
#include <hip/hip_bf16.h>
#include <math.h>

#define BB 16
#define NTOK 1024
#define CDIM 256
#define HEADS 8
#define HD 32
#define LOG2E 1.4426950408889634f
#define PSHIFT 18.0f

typedef __attribute__((ext_vector_type(8))) _Float16 half8;
typedef __attribute__((ext_vector_type(8))) unsigned short u16x8;
typedef __attribute__((ext_vector_type(4))) unsigned int u32x4;
typedef __attribute__((ext_vector_type(4))) float f32x4;

__device__ __forceinline__ unsigned short f2h(float f) {
  _Float16 h = (_Float16)f;
  return __builtin_bit_cast(unsigned short, h);
}
__device__ __forceinline__ half8 ldh8(const unsigned short* p) {
  return *reinterpret_cast<const half8*>(p);
}
__device__ __forceinline__ void gl_lds16(const unsigned short* g,
                                         unsigned short* l) {
  __builtin_amdgcn_global_load_lds(
      (const __attribute__((address_space(1))) unsigned int*)g,
      (__attribute__((address_space(3))) unsigned int*)l, 16, 0, 0);
}

// ---------------------------------------------------------------------------
__global__ __launch_bounds__(256) void cvt_x(const float* __restrict__ X,
                                             unsigned short* __restrict__ x16) {
  size_t base = ((size_t)blockIdx.x * 256 + threadIdx.x) * 8;
  float4 a = *(const float4*)(X + base);
  float4 b = *(const float4*)(X + base + 4);
  u16x8 o = {f2h(a.x), f2h(a.y), f2h(a.z), f2h(a.w),
             f2h(b.x), f2h(b.y), f2h(b.z), f2h(b.w)};
  *(u16x8*)(x16 + base) = o;
}

// Transpose weights into (N,K) fp16.
__global__ __launch_bounds__(256) void cvt_w(
    const float* __restrict__ Wq, const float* __restrict__ Wkv,
    const float* __restrict__ Wp, unsigned short* __restrict__ wt16,
    unsigned short* __restrict__ wp16) {
  int idx = blockIdx.x * 256 + threadIdx.x;  // 0 .. 262143
  float val; size_t dst; bool isp = false;
  if (idx < 65536) {
    int k = idx >> 8, n = idx & 255;
    val = Wq[idx]; dst = (size_t)n * 256 + k;
  } else if (idx < 196608) {
    int i2 = idx - 65536;
    int k = i2 >> 9, n2 = i2 & 511;
    val = Wkv[i2]; dst = (size_t)(256 + n2) * 256 + k;
  } else {
    int i3 = idx - 196608;
    int k = i3 >> 8, n = i3 & 255;
    val = Wp[i3]; dst = (size_t)n * 256 + k; isp = true;
  }
  unsigned short h = f2h(val);
  if (isp) wp16[dst] = h; else wt16[dst] = h;
}

// ---------------------------------------------------------------------------
__global__ __launch_bounds__(256) void bias_kernel(
    const float* __restrict__ affine, const float* __restrict__ atab,
    float* __restrict__ bias) {
  int idx = blockIdx.x * 256 + threadIdx.x;
  if (idx >= BB * NTOK) return;
  int b = idx >> 10, n = idx & (NTOK - 1);
  float cx = (float)(n & 31);
  float cy = (float)(n >> 5);
  const float* A = affine + b * 6;
  float egx = fmaf(A[0], 16.f, fmaf(A[1], 16.f, A[2]));
  float egy = fmaf(A[3], 16.f, fmaf(A[4], 16.f, A[5]));
  float ang = atan2f(cy - egy, cx - egx);
  float t = (ang + 3.14159265358979323846f) *
            (1.f / (2.f * 3.14159265358979323846f)) * 4.f;
  int bin = (int)t;
  bin = bin < 0 ? 0 : (bin > 4 ? 4 : bin);
  for (int h = 0; h < HEADS; ++h) {
    float a = atab[bin * HEADS + h];
    float s = 1.f / (1.f + __expf(-a));
    bias[((size_t)b * HEADS + h) * NTOK + n] = 1.f + s;
  }
}

// ---------------------------------------------------------------------------
// maskF: mask*log2e - PSHIFT, fragment order for 32-key tiles with even/odd
// split: key k -> slab (b4*64 + (k>>5)*2 + (k&1)), addr q*16 + ((k&31)>>1).
// ---------------------------------------------------------------------------
__global__ __launch_bounds__(256) void mask_prepF(const float* __restrict__ m,
                                                  float* __restrict__ mF) {
  int idx = blockIdx.x * 256 + threadIdx.x;  // thread per float4; 1,048,576
  int b4 = idx >> 18;
  int rem = idx & 262143;
  int q = rem >> 8;
  int k = (rem & 255) * 4;
  float4 v = *(const float4*)(m + ((size_t)b4 * NTOK + q) * NTOK + k);
  float4 o = {fmaf(v.x, LOG2E, -PSHIFT), fmaf(v.y, LOG2E, -PSHIFT),
              fmaf(v.z, LOG2E, -PSHIFT), fmaf(v.w, LOG2E, -PSHIFT)};
  int kt = k >> 5;            // 32-key tile
  int m0 = (k & 31) >> 1;     // even, since k % 4 == 0
  size_t base = ((size_t)(b4 * 64 + kt * 2)) * 16384 + q * 16 + m0;
  float2 e = {o.x, o.z};      // even keys k, k+2  -> fp=0 slab
  float2 d = {o.y, o.w};      // odd keys k+1, k+3 -> fp=1 slab
  *(float2*)(mF + base) = e;
  *(float2*)(mF + base + 16384) = d;
}

// ---------------------------------------------------------------------------
// QKV projection: round-12 structure (fp16 MFMA, 128x128/BK=32,
// 2-buffer __syncthreads dbuf, u16 LDS-bounce epilogue).
// ---------------------------------------------------------------------------
__global__ __launch_bounds__(512, 4) void gemm_qkv16(
    const unsigned short* __restrict__ x16, const unsigned short* __restrict__ wt16,
    const float* __restrict__ bq, const float* __restrict__ bkv,
    const float* __restrict__ bias, unsigned short* __restrict__ q16,
    unsigned short* __restrict__ k16, unsigned short* __restrict__ vt16) {
  __shared__ __align__(16) unsigned short SM[16384];  // 32 KB multi-use
  unsigned short* Xs = SM;            // [2][4096]
  unsigned short* Ws = SM + 8192;     // [2][4096]
  int tid = threadIdx.x;
  int w = tid >> 6, l = tid & 63;
  int row16 = l & 15, grp = l >> 4;
  int bid = blockIdx.x;
  int xcd = bid & 7, local = bid >> 3;        // 0..95
  int jb = local % 6, mb = xcd * 16 + local / 6;
  int j0 = jb * 128, m0 = mb * 128;
  int wm = w >> 1, wn = w & 1;

  auto stg = [&](int nb, int kt) {  // 1KB chunk per operand per wave
    int k0s = kt * 32;
    int row = w * 16 + (l >> 2);
    int ge = (((l & 3) * 16) ^ ((row & 3) << 4)) >> 1;
    gl_lds16(x16 + (size_t)(m0 + row) * 256 + k0s + ge, Xs + nb * 4096 + w * 512);
    gl_lds16(wt16 + (size_t)(j0 + row) * 256 + k0s + ge, Ws + nb * 4096 + w * 512);
  };
  auto off16 = [&](int row, int g) {
    return row * 32 + ((((g * 16) ^ ((row & 3) << 4))) >> 1);
  };

  stg(0, 0);
  __syncthreads();

  f32x4 acc[2][4];
#pragma unroll
  for (int i = 0; i < 2; ++i)
#pragma unroll
    for (int c = 0; c < 4; ++c) acc[i][c] = (f32x4){0.f, 0.f, 0.f, 0.f};

  for (int kt = 0; kt < 8; ++kt) {
    int cur = kt & 1;
    if (kt < 7) stg(cur ^ 1, kt + 1);
    half8 a0 = ldh8(Xs + cur * 4096 + off16(wm * 32 + row16, grp));
    half8 a1 = ldh8(Xs + cur * 4096 + off16(wm * 32 + 16 + row16, grp));
#pragma unroll
    for (int c = 0; c < 4; ++c) {
      half8 bh = ldh8(Ws + cur * 4096 + off16(wn * 64 + c * 16 + row16, grp));
      acc[0][c] = __builtin_amdgcn_mfma_f32_16x16x32_f16(a0, bh, acc[0][c], 0, 0, 0);
      acc[1][c] = __builtin_amdgcn_mfma_f32_16x16x32_f16(a1, bh, acc[1][c], 0, 0, 0);
    }
    __syncthreads();
  }

  // epilogue: bounce through SM as u16 [64][136], two 64-row halves
  const float scaleq = 0.17677669529663687f * LOG2E;
  int half_mine = wm >> 1;
  for (int half = 0; half < 2; ++half) {
    if (half_mine == half) {
#pragma unroll
      for (int i = 0; i < 2; ++i) {
#pragma unroll
        for (int c = 0; c < 4; ++c) {
          int col = wn * 64 + c * 16 + row16;
          int jg = j0 + col;
#pragma unroll
          for (int r = 0; r < 4; ++r) {
            int rowl = (wm & 1) * 32 + i * 16 + grp * 4 + r;
            int m = m0 + half * 64 + rowl;
            int b = m >> 10, n = m & (NTOK - 1);
            float val = acc[i][c][r];
            unsigned short o;
            if (jb < 2)
              o = f2h((val + bq[jg]) * scaleq *
                      bias[((size_t)b * HEADS + (jg >> 5)) * NTOK + n]);
            else
              o = f2h(val + bkv[jg - CDIM]);
            SM[rowl * 136 + col] = o;
          }
        }
      }
    }
    __syncthreads();
    if (jb < 4) {
#pragma unroll
      for (int it = 0; it < 2; ++it) {
        int lin = it * 512 + tid;
        int rowb = lin >> 4, oct = lin & 15;
        u16x8 v = *(const u16x8*)&SM[rowb * 136 + oct * 8];
        int m = m0 + half * 64 + rowb;
        int b = m >> 10, n = m & (NTOK - 1);
        int jg = j0 + oct * 8;
        unsigned short* dst; int h, d;
        if (jb < 2) { h = jg >> 5; d = jg & 31; dst = q16; }
        else { int c2 = jg - CDIM; h = c2 >> 5; d = c2 & 31; dst = k16; }
        *(u16x8*)(dst + (((size_t)b * HEADS + h) * NTOK + n) * HD + d) = v;
      }
    } else {
#pragma unroll
      for (int it = 0; it < 2; ++it) {
        int lin = it * 512 + tid;
        int noct = lin >> 7, jl = lin & 127;
        u16x8 v;
#pragma unroll
        for (int e = 0; e < 8; ++e) v[e] = SM[(noct * 8 + e) * 136 + jl];
        int c3 = j0 + jl - 2 * CDIM;
        int h = c3 >> 5, d = c3 & 31;
        int n0 = m0 + half * 64 + noct * 8;
        int b = n0 >> 10, nn = n0 & (NTOK - 1);
        *(u16x8*)(vt16 + (((size_t)b * HEADS + h) * HD + d) * NTOK + nn) = v;
      }
    }
    __syncthreads();
  }
}

// ---------------------------------------------------------------------------
// Flash attention, head-sharing blocks: block = (b, 64-q tile, head-group
// of 4). 8 waves = 4 head-locals x 2 q-halves; waves with the same q-half
// read IDENTICAL mask addresses -> guaranteed L1 amortization (4x).
// KVBLK=32, per-head K/V staged by own waves; K even/odd-permuted at source
// so the PV A-fragment is built fully in registers (no P LDS).
// LDS swizzle: slot = grp ^ ((row>>1)&3) on 64B rows (2-way, free).
// ---------------------------------------------------------------------------
__global__ __launch_bounds__(512, 4) void attn16(
    const unsigned short* __restrict__ q16, const unsigned short* __restrict__ k16,
    const unsigned short* __restrict__ vt16, const float* __restrict__ maskF,
    unsigned short* __restrict__ ao16) {
  __shared__ __align__(16) unsigned short KT[2][4][1024];  // [buf][head][32k x 32d]
  __shared__ __align__(16) unsigned short VT[2][4][1024];  // [buf][head][32d x 32k]

  int tid = threadIdx.x;
  int w = tid >> 6, l = tid & 63;
  int row16 = l & 15, grp = l >> 4;
  int bid = blockIdx.x;
  // bid = inner_global*8 + (slabgroup%8): mask-slab-sharing blocks colocate.
  int g = (bid >> 6) * 8 + (bid & 7);   // 0..63 slab group
  int inner = (bid >> 3) & 7;
  int qt = g >> 2, b4 = g & 3;
  int brep = inner >> 1, hg = inner & 1;
  int b = brep * 4 + b4;
  int hl = w >> 1, qh = w & 1;
  int head = hg * 4 + hl;
  int bh = b * HEADS + head;
  int qbase = qt * 64 + qh * 32;

  // Q B-operands: 2 x 16-q fragments
  half8 bq[2];
#pragma unroll
  for (int qb = 0; qb < 2; ++qb)
    bq[qb] = ldh8(q16 + ((size_t)bh * NTOK + qbase + qb * 16 + row16) * HD +
                  grp * 8);

  const float* mFb = maskF + (size_t)b4 * 64 * 16384;

  f32x4 acc[2][2];
#pragma unroll
  for (int i = 0; i < 2; ++i)
#pragma unroll
    for (int j = 0; j < 2; ++j) acc[i][j] = (f32x4){0.f, 0.f, 0.f, 0.f};
  float lsum[2] = {0.f, 0.f};

  // swizzled LDS read offset (u16): 64B rows, slot = grp ^ ((row>>1)&3)
  auto off32 = [&](int row, int gg) {
    return row * 32 + ((gg ^ ((row >> 1) & 3)) << 3);
  };

  auto stage = [&](int nb, int kt2) {  // 2 gl_lds per wave (own head)
    int k0n = (kt2 & 31) * 32;
    // K: LDS row r = qh*16 + (l>>2) holds key 2*(l>>2)+qh (even/odd perm)
    int key = 2 * (l >> 2) + qh;
    int sk = (l & 3) ^ ((qh * 8 + (l >> 3)) & 3);
    gl_lds16(k16 + ((size_t)bh * NTOK + k0n + key) * HD + sk * 8,
             &KT[nb][hl][qh * 512]);
    // V^T: LDS d-row dl = qh*16 + (l>>2)
    int dl = qh * 16 + (l >> 2);
    int sv = (l & 3) ^ ((qh * 8 + (l >> 3)) & 3);
    gl_lds16(vt16 + ((size_t)bh * HD + dl) * NTOK + k0n + sv * 8,
             &VT[nb][hl][qh * 512]);
  };

  stage(0, 0);
  __syncthreads();

  for (int kt = 0; kt < 32; ++kt) {
    int cur = kt & 1;
    if (kt < 31) stage(cur ^ 1, kt + 1);

    // K fragments (fp=0: even keys, fp=1: odd) and V fragments: loaded once,
    // reused by both q-sub-blocks.
    half8 kf0 = ldh8(&KT[cur][hl][off32(row16, grp)]);
    half8 kf1 = ldh8(&KT[cur][hl][off32(16 + row16, grp)]);
    half8 v0 = ldh8(&VT[cur][hl][off32(row16, grp)]);
    half8 v1 = ldh8(&VT[cur][hl][off32(16 + row16, grp)]);

#pragma unroll
    for (int qb = 0; qb < 2; ++qb) {
      const float* mp = mFb + (size_t)(kt * 2) * 16384 +
                        (qbase + qb * 16 + row16) * 16 + grp * 4;
      f32x4 mC0 = *(const f32x4*)mp;
      f32x4 mC1 = *(const f32x4*)(mp + 16384);
      f32x4 s0 = __builtin_amdgcn_mfma_f32_16x16x32_f16(kf0, bq[qb], mC0, 0, 0, 0);
      f32x4 s1 = __builtin_amdgcn_mfma_f32_16x16x32_f16(kf1, bq[qb], mC1, 0, 0, 0);
      f32x4 e0, e1;
#pragma unroll
      for (int r = 0; r < 4; ++r) {
        e0[r] = __builtin_amdgcn_exp2f(s0[r]);
        e1[r] = __builtin_amdgcn_exp2f(s1[r]);
      }
      lsum[qb] += ((e0[0] + e1[0]) + (e0[1] + e1[1])) +
                  ((e0[2] + e1[2]) + (e0[3] + e1[3]));
      u32x4 pk;
#pragma unroll
      for (int r = 0; r < 4; ++r)
        pk[r] = __builtin_bit_cast(unsigned,
                                   __builtin_amdgcn_cvt_pkrtz(e0[r], e1[r]));
      half8 pa = __builtin_bit_cast(half8, pk);  // keys 8grp..8grp+7
      acc[qb][0] = __builtin_amdgcn_mfma_f32_16x16x32_f16(pa, v0, acc[qb][0], 0, 0, 0);
      acc[qb][1] = __builtin_amdgcn_mfma_f32_16x16x32_f16(pa, v1, acc[qb][1], 0, 0, 0);
    }
    __syncthreads();
  }

  // reduce lsum across the 4 grp slices (value depends only on row16)
#pragma unroll
  for (int qb = 0; qb < 2; ++qb) {
    lsum[qb] += __shfl_xor(lsum[qb], 16);
    lsum[qb] += __shfl_xor(lsum[qb], 32);
  }
#pragma unroll
  for (int qb = 0; qb < 2; ++qb) {
#pragma unroll
    for (int r = 0; r < 4; ++r) {
      float lr = __shfl(lsum[qb], grp * 4 + r, 16);
      float inv = 1.f / lr;
      int qrow = qbase + qb * 16 + grp * 4 + r;
      size_t obase = ((size_t)b * NTOK + qrow) * CDIM + head * HD;
      ao16[obase + row16] = f2h(acc[qb][0][r] * inv);
      ao16[obase + 16 + row16] = f2h(acc[qb][1][r] * inv);
    }
  }
}

// ---------------------------------------------------------------------------
// Output projection: round-12 structure.
// ---------------------------------------------------------------------------
__global__ __launch_bounds__(512, 4) void gemm_out16(
    const unsigned short* __restrict__ a16, const unsigned short* __restrict__ wp16,
    const float* __restrict__ bp, float* __restrict__ out) {
  __shared__ __align__(16) unsigned short SM[16384];
  unsigned short* Xs = SM;
  unsigned short* Ws = SM + 8192;
  int tid = threadIdx.x;
  int w = tid >> 6, l = tid & 63;
  int row16 = l & 15, grp = l >> 4;
  int bid = blockIdx.x;
  int xcd = bid & 7, local = bid >> 3;
  int jb = local & 1, mb = xcd * 16 + (local >> 1);
  int j0 = jb * 128, m0 = mb * 128;
  int wm = w >> 1, wn = w & 1;

  auto stg = [&](int nb, int kt) {
    int k0s = kt * 32;
    int row = w * 16 + (l >> 2);
    int ge = (((l & 3) * 16) ^ ((row & 3) << 4)) >> 1;
    gl_lds16(a16 + (size_t)(m0 + row) * 256 + k0s + ge, Xs + nb * 4096 + w * 512);
    gl_lds16(wp16 + (size_t)(j0 + row) * 256 + k0s + ge, Ws + nb * 4096 + w * 512);
  };
  auto off16 = [&](int row, int g) {
    return row * 32 + ((((g * 16) ^ ((row & 3) << 4))) >> 1);
  };

  stg(0, 0);
  __syncthreads();

  f32x4 acc[2][4];
#pragma unroll
  for (int i = 0; i < 2; ++i)
#pragma unroll
    for (int c = 0; c < 4; ++c) acc[i][c] = (f32x4){0.f, 0.f, 0.f, 0.f};

  for (int kt = 0; kt < 8; ++kt) {
    int cur = kt & 1;
    if (kt < 7) stg(cur ^ 1, kt + 1);
    half8 a0 = ldh8(Xs + cur * 4096 + off16(wm * 32 + row16, grp));
    half8 a1 = ldh8(Xs + cur * 4096 + off16(wm * 32 + 16 + row16, grp));
#pragma unroll
    for (int c = 0; c < 4; ++c) {
      half8 bh = ldh8(Ws + cur * 4096 + off16(wn * 64 + c * 16 + row16, grp));
      acc[0][c] = __builtin_amdgcn_mfma_f32_16x16x32_f16(a0, bh, acc[0][c], 0, 0, 0);
      acc[1][c] = __builtin_amdgcn_mfma_f32_16x16x32_f16(a1, bh, acc[1][c], 0, 0, 0);
    }
    __syncthreads();
  }

#pragma unroll
  for (int i = 0; i < 2; ++i) {
    int ng = m0 + wm * 32 + i * 16 + grp * 4;
#pragma unroll
    for (int c = 0; c < 4; ++c) {
      int jg = j0 + wn * 64 + c * 16 + row16;
      float bias = bp[jg];
#pragma unroll
      for (int r = 0; r < 4; ++r) {
        out[(size_t)(ng + r) * CDIM + jg] = acc[i][c][r] + bias;
      }
    }
  }
}

// ---------------------------------------------------------------------------
extern "C" void kernel_launch(void* const* d_in, const int* in_sizes, int n_in,
                              void* d_out, int out_size, void* d_ws,
                              size_t ws_size, hipStream_t stream) {
  const float* x = (const float*)d_in[0];
  const float* mask = (const float*)d_in[1];
  const float* affine = (const float*)d_in[2];
  const float* Wq = (const float*)d_in[3];
  const float* bq = (const float*)d_in[4];
  const float* Wkv = (const float*)d_in[5];
  const float* bkv = (const float*)d_in[6];
  const float* Wp = (const float*)d_in[7];
  const float* bp = (const float*)d_in[8];
  const float* atab = (const float*)d_in[9];
  float* out = (float*)d_out;

  const size_t bhnd = (size_t)BB * HEADS * NTOK * HD;  // 4,194,304
  unsigned short* q16 = (unsigned short*)d_ws;
  unsigned short* k16 = q16 + bhnd;
  unsigned short* vt16 = k16 + bhnd;
  unsigned short* x16 = vt16 + bhnd;     // aliased as ao16 after qkv
  unsigned short* wt16 = x16 + bhnd;     // 768*256
  unsigned short* wp16 = wt16 + 768 * 256;
  float* bias = (float*)(wp16 + 256 * 256);
  float* maskF = bias + (size_t)BB * HEADS * NTOK;

  cvt_x<<<2048, 256, 0, stream>>>(x, x16);
  cvt_w<<<1024, 256, 0, stream>>>(Wq, Wkv, Wp, wt16, wp16);
  bias_kernel<<<64, 256, 0, stream>>>(affine, atab, bias);
  mask_prepF<<<4096, 256, 0, stream>>>(mask, maskF);
  gemm_qkv16<<<768, 512, 0, stream>>>(x16, wt16, bq, bkv, bias, q16, k16, vt16);
  attn16<<<512, 512, 0, stream>>>(q16, k16, vt16, maskF, x16);
  gemm_out16<<<256, 512, 0, stream>>>(x16, wp16, bp, out);
}

// Round 18
// 89.339 us; speedup vs baseline: 1.1243x; 1.0741x over previous
//
#include <hip/hip_runtime.h>
#include <hip/hip_bf16.h>
#include <math.h>

#define BB 16
#define NTOK 1024
#define CDIM 256
#define HEADS 8
#define HD 32
#define LOG2E 1.4426950408889634f
#define PSHIFT 18.0f

typedef __attribute__((ext_vector_type(8))) _Float16 half8;
typedef __attribute__((ext_vector_type(8))) unsigned short u16x8;
typedef __attribute__((ext_vector_type(4))) unsigned int u32x4;
typedef __attribute__((ext_vector_type(4))) float f32x4;

__device__ __forceinline__ unsigned short f2h(float f) {
  _Float16 h = (_Float16)f;
  return __builtin_bit_cast(unsigned short, h);
}
__device__ __forceinline__ half8 ldh8(const unsigned short* p) {
  return *reinterpret_cast<const half8*>(p);
}
__device__ __forceinline__ void gl_lds16(const void* g, void* l) {
  __builtin_amdgcn_global_load_lds(
      (const __attribute__((address_space(1))) unsigned int*)g,
      (__attribute__((address_space(3))) unsigned int*)l, 16, 0, 0);
}

// ---------------------------------------------------------------------------
__global__ __launch_bounds__(256) void cvt_x(const float* __restrict__ X,
                                             unsigned short* __restrict__ x16) {
  size_t base = ((size_t)blockIdx.x * 256 + threadIdx.x) * 8;
  float4 a = *(const float4*)(X + base);
  float4 b = *(const float4*)(X + base + 4);
  u16x8 o = {f2h(a.x), f2h(a.y), f2h(a.z), f2h(a.w),
             f2h(b.x), f2h(b.y), f2h(b.z), f2h(b.w)};
  *(u16x8*)(x16 + base) = o;
}

// Transpose weights into (N,K) fp16.
__global__ __launch_bounds__(256) void cvt_w(
    const float* __restrict__ Wq, const float* __restrict__ Wkv,
    const float* __restrict__ Wp, unsigned short* __restrict__ wt16,
    unsigned short* __restrict__ wp16) {
  int idx = blockIdx.x * 256 + threadIdx.x;  // 0 .. 262143
  float val; size_t dst; bool isp = false;
  if (idx < 65536) {
    int k = idx >> 8, n = idx & 255;
    val = Wq[idx]; dst = (size_t)n * 256 + k;
  } else if (idx < 196608) {
    int i2 = idx - 65536;
    int k = i2 >> 9, n2 = i2 & 511;
    val = Wkv[i2]; dst = (size_t)(256 + n2) * 256 + k;
  } else {
    int i3 = idx - 196608;
    int k = i3 >> 8, n = i3 & 255;
    val = Wp[i3]; dst = (size_t)n * 256 + k; isp = true;
  }
  unsigned short h = f2h(val);
  if (isp) wp16[dst] = h; else wt16[dst] = h;
}

// ---------------------------------------------------------------------------
__global__ __launch_bounds__(256) void bias_kernel(
    const float* __restrict__ affine, const float* __restrict__ atab,
    float* __restrict__ bias) {
  int idx = blockIdx.x * 256 + threadIdx.x;
  if (idx >= BB * NTOK) return;
  int b = idx >> 10, n = idx & (NTOK - 1);
  float cx = (float)(n & 31);
  float cy = (float)(n >> 5);
  const float* A = affine + b * 6;
  float egx = fmaf(A[0], 16.f, fmaf(A[1], 16.f, A[2]));
  float egy = fmaf(A[3], 16.f, fmaf(A[4], 16.f, A[5]));
  float ang = atan2f(cy - egy, cx - egx);
  float t = (ang + 3.14159265358979323846f) *
            (1.f / (2.f * 3.14159265358979323846f)) * 4.f;
  int bin = (int)t;
  bin = bin < 0 ? 0 : (bin > 4 ? 4 : bin);
  for (int h = 0; h < HEADS; ++h) {
    float a = atab[bin * HEADS + h];
    float s = 1.f / (1.f + __expf(-a));
    bias[((size_t)b * HEADS + h) * NTOK + n] = 1.f + s;
  }
}

// ---------------------------------------------------------------------------
// maskF: mask*log2e - PSHIFT, fragment order for 32-key tiles with even/odd
// split: key k -> slab (b4*64 + (k>>5)*2 + (k&1)), addr q*16 + ((k&31)>>1).
// ---------------------------------------------------------------------------
__global__ __launch_bounds__(256) void mask_prepF(const float* __restrict__ m,
                                                  float* __restrict__ mF) {
  int idx = blockIdx.x * 256 + threadIdx.x;  // thread per float4; 1,048,576
  int b4 = idx >> 18;
  int rem = idx & 262143;
  int q = rem >> 8;
  int k = (rem & 255) * 4;
  float4 v = *(const float4*)(m + ((size_t)b4 * NTOK + q) * NTOK + k);
  float4 o = {fmaf(v.x, LOG2E, -PSHIFT), fmaf(v.y, LOG2E, -PSHIFT),
              fmaf(v.z, LOG2E, -PSHIFT), fmaf(v.w, LOG2E, -PSHIFT)};
  int kt = k >> 5;            // 32-key tile
  int m0 = (k & 31) >> 1;     // even, since k % 4 == 0
  size_t base = ((size_t)(b4 * 64 + kt * 2)) * 16384 + q * 16 + m0;
  float2 e = {o.x, o.z};      // even keys k, k+2  -> fp=0 slab
  float2 d = {o.y, o.w};      // odd keys k+1, k+3 -> fp=1 slab
  *(float2*)(mF + base) = e;
  *(float2*)(mF + base + 16384) = d;
}

// ---------------------------------------------------------------------------
// QKV projection: round-12 structure (fp16 MFMA, 128x128/BK=32,
// 2-buffer __syncthreads dbuf, u16 LDS-bounce epilogue).
// ---------------------------------------------------------------------------
__global__ __launch_bounds__(512, 4) void gemm_qkv16(
    const unsigned short* __restrict__ x16, const unsigned short* __restrict__ wt16,
    const float* __restrict__ bq, const float* __restrict__ bkv,
    const float* __restrict__ bias, unsigned short* __restrict__ q16,
    unsigned short* __restrict__ k16, unsigned short* __restrict__ vt16) {
  __shared__ __align__(16) unsigned short SM[16384];  // 32 KB multi-use
  unsigned short* Xs = SM;            // [2][4096]
  unsigned short* Ws = SM + 8192;     // [2][4096]
  int tid = threadIdx.x;
  int w = tid >> 6, l = tid & 63;
  int row16 = l & 15, grp = l >> 4;
  int bid = blockIdx.x;
  int xcd = bid & 7, local = bid >> 3;        // 0..95
  int jb = local % 6, mb = xcd * 16 + local / 6;
  int j0 = jb * 128, m0 = mb * 128;
  int wm = w >> 1, wn = w & 1;

  auto stg = [&](int nb, int kt) {  // 1KB chunk per operand per wave
    int k0s = kt * 32;
    int row = w * 16 + (l >> 2);
    int ge = (((l & 3) * 16) ^ ((row & 3) << 4)) >> 1;
    gl_lds16(x16 + (size_t)(m0 + row) * 256 + k0s + ge, Xs + nb * 4096 + w * 512);
    gl_lds16(wt16 + (size_t)(j0 + row) * 256 + k0s + ge, Ws + nb * 4096 + w * 512);
  };
  auto off16 = [&](int row, int g) {
    return row * 32 + ((((g * 16) ^ ((row & 3) << 4))) >> 1);
  };

  stg(0, 0);
  __syncthreads();

  f32x4 acc[2][4];
#pragma unroll
  for (int i = 0; i < 2; ++i)
#pragma unroll
    for (int c = 0; c < 4; ++c) acc[i][c] = (f32x4){0.f, 0.f, 0.f, 0.f};

  for (int kt = 0; kt < 8; ++kt) {
    int cur = kt & 1;
    if (kt < 7) stg(cur ^ 1, kt + 1);
    half8 a0 = ldh8(Xs + cur * 4096 + off16(wm * 32 + row16, grp));
    half8 a1 = ldh8(Xs + cur * 4096 + off16(wm * 32 + 16 + row16, grp));
#pragma unroll
    for (int c = 0; c < 4; ++c) {
      half8 bh = ldh8(Ws + cur * 4096 + off16(wn * 64 + c * 16 + row16, grp));
      acc[0][c] = __builtin_amdgcn_mfma_f32_16x16x32_f16(a0, bh, acc[0][c], 0, 0, 0);
      acc[1][c] = __builtin_amdgcn_mfma_f32_16x16x32_f16(a1, bh, acc[1][c], 0, 0, 0);
    }
    __syncthreads();
  }

  // epilogue: bounce through SM as u16 [64][136], two 64-row halves
  const float scaleq = 0.17677669529663687f * LOG2E;
  int half_mine = wm >> 1;
  for (int half = 0; half < 2; ++half) {
    if (half_mine == half) {
#pragma unroll
      for (int i = 0; i < 2; ++i) {
#pragma unroll
        for (int c = 0; c < 4; ++c) {
          int col = wn * 64 + c * 16 + row16;
          int jg = j0 + col;
#pragma unroll
          for (int r = 0; r < 4; ++r) {
            int rowl = (wm & 1) * 32 + i * 16 + grp * 4 + r;
            int m = m0 + half * 64 + rowl;
            int b = m >> 10, n = m & (NTOK - 1);
            float val = acc[i][c][r];
            unsigned short o;
            if (jb < 2)
              o = f2h((val + bq[jg]) * scaleq *
                      bias[((size_t)b * HEADS + (jg >> 5)) * NTOK + n]);
            else
              o = f2h(val + bkv[jg - CDIM]);
            SM[rowl * 136 + col] = o;
          }
        }
      }
    }
    __syncthreads();
    if (jb < 4) {
#pragma unroll
      for (int it = 0; it < 2; ++it) {
        int lin = it * 512 + tid;
        int rowb = lin >> 4, oct = lin & 15;
        u16x8 v = *(const u16x8*)&SM[rowb * 136 + oct * 8];
        int m = m0 + half * 64 + rowb;
        int b = m >> 10, n = m & (NTOK - 1);
        int jg = j0 + oct * 8;
        unsigned short* dst; int h, d;
        if (jb < 2) { h = jg >> 5; d = jg & 31; dst = q16; }
        else { int c2 = jg - CDIM; h = c2 >> 5; d = c2 & 31; dst = k16; }
        *(u16x8*)(dst + (((size_t)b * HEADS + h) * NTOK + n) * HD + d) = v;
      }
    } else {
#pragma unroll
      for (int it = 0; it < 2; ++it) {
        int lin = it * 512 + tid;
        int noct = lin >> 7, jl = lin & 127;
        u16x8 v;
#pragma unroll
        for (int e = 0; e < 8; ++e) v[e] = SM[(noct * 8 + e) * 136 + jl];
        int c3 = j0 + jl - 2 * CDIM;
        int h = c3 >> 5, d = c3 & 31;
        int n0 = m0 + half * 64 + noct * 8;
        int b = n0 >> 10, nn = n0 & (NTOK - 1);
        *(u16x8*)(vt16 + (((size_t)b * HEADS + h) * HD + d) * NTOK + nn) = v;
      }
    }
    __syncthreads();
  }
}

// ---------------------------------------------------------------------------
// Flash attention, head-sharing blocks + mask staged through LDS:
// block = (b, 64-q tile, head-group of 4); 8 waves = 4 head x 2 q-half.
// Three streams in the async double-buffer: K (even/odd-permuted), V^T,
// and the 8KB/tile mask fragment (shared by all 4 heads).
// ---------------------------------------------------------------------------
__global__ __launch_bounds__(512, 4) void attn16(
    const unsigned short* __restrict__ q16, const unsigned short* __restrict__ k16,
    const unsigned short* __restrict__ vt16, const float* __restrict__ maskF,
    unsigned short* __restrict__ ao16) {
  __shared__ __align__(16) unsigned short KT[2][4][1024];  // [buf][head][32k x 32d]
  __shared__ __align__(16) unsigned short VT[2][4][1024];  // [buf][head][32d x 32k]
  __shared__ __align__(16) float MT[2][2][1024];           // [buf][slab][64q x 16]

  int tid = threadIdx.x;
  int w = tid >> 6, l = tid & 63;
  int row16 = l & 15, grp = l >> 4;
  int bid = blockIdx.x;
  int g = (bid >> 6) * 8 + (bid & 7);   // 0..63 slab group
  int inner = (bid >> 3) & 7;
  int qt = g >> 2, b4 = g & 3;
  int brep = inner >> 1, hg = inner & 1;
  int b = brep * 4 + b4;
  int hl = w >> 1, qh = w & 1;
  int head = hg * 4 + hl;
  int bh = b * HEADS + head;
  int q0g = qt * 64;
  int qbase = q0g + qh * 32;

  // Q B-operands: 2 x 16-q fragments
  half8 bq[2];
#pragma unroll
  for (int qb = 0; qb < 2; ++qb)
    bq[qb] = ldh8(q16 + ((size_t)bh * NTOK + qbase + qb * 16 + row16) * HD +
                  grp * 8);

  const float* mFb = maskF + (size_t)b4 * 64 * 16384;

  f32x4 acc[2][2];
#pragma unroll
  for (int i = 0; i < 2; ++i)
#pragma unroll
    for (int j = 0; j < 2; ++j) acc[i][j] = (f32x4){0.f, 0.f, 0.f, 0.f};
  float lsum[2] = {0.f, 0.f};

  // K/V swizzled LDS read offset (u16): 64B rows, slot = grp ^ ((row>>1)&3)
  auto off32 = [&](int row, int gg) {
    return row * 32 + ((gg ^ ((row >> 1) & 3)) << 3);
  };
  // mask swizzle: phys 16B slot = (g + qr + (qr>>2)) & 3  (2-way, free)
  auto moff = [&](int qr, int gg) {
    return qr * 16 + (((gg + qr + (qr >> 2)) & 3) << 2);
  };

  auto stage = [&](int nb, int kt2) {  // 3 gl_lds per wave
    int k0n = (kt2 & 31) * 32;
    // K: LDS row r = qh*16 + (l>>2) holds key 2*(l>>2)+qh (even/odd perm)
    int key = 2 * (l >> 2) + qh;
    int sk = (l & 3) ^ ((qh * 8 + (l >> 3)) & 3);
    gl_lds16(k16 + ((size_t)bh * NTOK + k0n + key) * HD + sk * 8,
             &KT[nb][hl][qh * 512]);
    // V^T: LDS d-row dl = qh*16 + (l>>2)
    int dl = qh * 16 + (l >> 2);
    int sv = (l & 3) ^ ((qh * 8 + (l >> 3)) & 3);
    gl_lds16(vt16 + ((size_t)bh * HD + dl) * NTOK + k0n + sv * 8,
             &VT[nb][hl][qh * 512]);
    // mask: wave w stages chunk w (1KB): slab = w>>2, rows (w&3)*16..+15
    int slab = w >> 2;
    int qq = (w & 3) * 16 + (l >> 2);
    int srcslot = ((l & 3) - qq - (qq >> 2)) & 3;
    const float* msrc = mFb + (size_t)((kt2 & 31) * 2 + slab) * 16384 +
                        (q0g + qq) * 16 + srcslot * 4;
    gl_lds16(msrc, &MT[nb][slab][(w & 3) * 256]);
  };

  stage(0, 0);
  __syncthreads();

  for (int kt = 0; kt < 32; ++kt) {
    int cur = kt & 1;
    if (kt < 31) stage(cur ^ 1, kt + 1);

    // K/V fragments: loaded once, reused by both q-sub-blocks.
    half8 kf0 = ldh8(&KT[cur][hl][off32(row16, grp)]);
    half8 kf1 = ldh8(&KT[cur][hl][off32(16 + row16, grp)]);
    half8 v0 = ldh8(&VT[cur][hl][off32(row16, grp)]);
    half8 v1 = ldh8(&VT[cur][hl][off32(16 + row16, grp)]);

#pragma unroll
    for (int qb = 0; qb < 2; ++qb) {
      int qr = qh * 32 + qb * 16 + row16;
      f32x4 mC0 = *(const f32x4*)&MT[cur][0][moff(qr, grp)];
      f32x4 mC1 = *(const f32x4*)&MT[cur][1][moff(qr, grp)];
      f32x4 s0 = __builtin_amdgcn_mfma_f32_16x16x32_f16(kf0, bq[qb], mC0, 0, 0, 0);
      f32x4 s1 = __builtin_amdgcn_mfma_f32_16x16x32_f16(kf1, bq[qb], mC1, 0, 0, 0);
      f32x4 e0, e1;
#pragma unroll
      for (int r = 0; r < 4; ++r) {
        e0[r] = __builtin_amdgcn_exp2f(s0[r]);
        e1[r] = __builtin_amdgcn_exp2f(s1[r]);
      }
      lsum[qb] += ((e0[0] + e1[0]) + (e0[1] + e1[1])) +
                  ((e0[2] + e1[2]) + (e0[3] + e1[3]));
      u32x4 pk;
#pragma unroll
      for (int r = 0; r < 4; ++r)
        pk[r] = __builtin_bit_cast(unsigned,
                                   __builtin_amdgcn_cvt_pkrtz(e0[r], e1[r]));
      half8 pa = __builtin_bit_cast(half8, pk);  // keys 8grp..8grp+7
      acc[qb][0] = __builtin_amdgcn_mfma_f32_16x16x32_f16(pa, v0, acc[qb][0], 0, 0, 0);
      acc[qb][1] = __builtin_amdgcn_mfma_f32_16x16x32_f16(pa, v1, acc[qb][1], 0, 0, 0);
    }
    __syncthreads();
  }

  // reduce lsum across the 4 grp slices (value depends only on row16)
#pragma unroll
  for (int qb = 0; qb < 2; ++qb) {
    lsum[qb] += __shfl_xor(lsum[qb], 16);
    lsum[qb] += __shfl_xor(lsum[qb], 32);
  }
#pragma unroll
  for (int qb = 0; qb < 2; ++qb) {
#pragma unroll
    for (int r = 0; r < 4; ++r) {
      float lr = __shfl(lsum[qb], grp * 4 + r, 16);
      float inv = 1.f / lr;
      int qrow = qbase + qb * 16 + grp * 4 + r;
      size_t obase = ((size_t)b * NTOK + qrow) * CDIM + head * HD;
      ao16[obase + row16] = f2h(acc[qb][0][r] * inv);
      ao16[obase + 16 + row16] = f2h(acc[qb][1][r] * inv);
    }
  }
}

// ---------------------------------------------------------------------------
// Output projection: round-12 structure.
// ---------------------------------------------------------------------------
__global__ __launch_bounds__(512, 4) void gemm_out16(
    const unsigned short* __restrict__ a16, const unsigned short* __restrict__ wp16,
    const float* __restrict__ bp, float* __restrict__ out) {
  __shared__ __align__(16) unsigned short SM[16384];
  unsigned short* Xs = SM;
  unsigned short* Ws = SM + 8192;
  int tid = threadIdx.x;
  int w = tid >> 6, l = tid & 63;
  int row16 = l & 15, grp = l >> 4;
  int bid = blockIdx.x;
  int xcd = bid & 7, local = bid >> 3;
  int jb = local & 1, mb = xcd * 16 + (local >> 1);
  int j0 = jb * 128, m0 = mb * 128;
  int wm = w >> 1, wn = w & 1;

  auto stg = [&](int nb, int kt) {
    int k0s = kt * 32;
    int row = w * 16 + (l >> 2);
    int ge = (((l & 3) * 16) ^ ((row & 3) << 4)) >> 1;
    gl_lds16(a16 + (size_t)(m0 + row) * 256 + k0s + ge, Xs + nb * 4096 + w * 512);
    gl_lds16(wp16 + (size_t)(j0 + row) * 256 + k0s + ge, Ws + nb * 4096 + w * 512);
  };
  auto off16 = [&](int row, int g) {
    return row * 32 + ((((g * 16) ^ ((row & 3) << 4))) >> 1);
  };

  stg(0, 0);
  __syncthreads();

  f32x4 acc[2][4];
#pragma unroll
  for (int i = 0; i < 2; ++i)
#pragma unroll
    for (int c = 0; c < 4; ++c) acc[i][c] = (f32x4){0.f, 0.f, 0.f, 0.f};

  for (int kt = 0; kt < 8; ++kt) {
    int cur = kt & 1;
    if (kt < 7) stg(cur ^ 1, kt + 1);
    half8 a0 = ldh8(Xs + cur * 4096 + off16(wm * 32 + row16, grp));
    half8 a1 = ldh8(Xs + cur * 4096 + off16(wm * 32 + 16 + row16, grp));
#pragma unroll
    for (int c = 0; c < 4; ++c) {
      half8 bh = ldh8(Ws + cur * 4096 + off16(wn * 64 + c * 16 + row16, grp));
      acc[0][c] = __builtin_amdgcn_mfma_f32_16x16x32_f16(a0, bh, acc[0][c], 0, 0, 0);
      acc[1][c] = __builtin_amdgcn_mfma_f32_16x16x32_f16(a1, bh, acc[1][c], 0, 0, 0);
    }
    __syncthreads();
  }

#pragma unroll
  for (int i = 0; i < 2; ++i) {
    int ng = m0 + wm * 32 + i * 16 + grp * 4;
#pragma unroll
    for (int c = 0; c < 4; ++c) {
      int jg = j0 + wn * 64 + c * 16 + row16;
      float bias = bp[jg];
#pragma unroll
      for (int r = 0; r < 4; ++r) {
        out[(size_t)(ng + r) * CDIM + jg] = acc[i][c][r] + bias;
      }
    }
  }
}

// ---------------------------------------------------------------------------
extern "C" void kernel_launch(void* const* d_in, const int* in_sizes, int n_in,
                              void* d_out, int out_size, void* d_ws,
                              size_t ws_size, hipStream_t stream) {
  const float* x = (const float*)d_in[0];
  const float* mask = (const float*)d_in[1];
  const float* affine = (const float*)d_in[2];
  const float* Wq = (const float*)d_in[3];
  const float* bq = (const float*)d_in[4];
  const float* Wkv = (const float*)d_in[5];
  const float* bkv = (const float*)d_in[6];
  const float* Wp = (const float*)d_in[7];
  const float* bp = (const float*)d_in[8];
  const float* atab = (const float*)d_in[9];
  float* out = (float*)d_out;

  const size_t bhnd = (size_t)BB * HEADS * NTOK * HD;  // 4,194,304
  unsigned short* q16 = (unsigned short*)d_ws;
  unsigned short* k16 = q16 + bhnd;
  unsigned short* vt16 = k16 + bhnd;
  unsigned short* x16 = vt16 + bhnd;     // aliased as ao16 after qkv
  unsigned short* wt16 = x16 + bhnd;     // 768*256
  unsigned short* wp16 = wt16 + 768 * 256;
  float* bias = (float*)(wp16 + 256 * 256);
  float* maskF = bias + (size_t)BB * HEADS * NTOK;

  cvt_x<<<2048, 256, 0, stream>>>(x, x16);
  cvt_w<<<1024, 256, 0, stream>>>(Wq, Wkv, Wp, wt16, wp16);
  bias_kernel<<<64, 256, 0, stream>>>(affine, atab, bias);
  mask_prepF<<<4096, 256, 0, stream>>>(mask, maskF);
  gemm_qkv16<<<768, 512, 0, stream>>>(x16, wt16, bq, bkv, bias, q16, k16, vt16);
  attn16<<<512, 512, 0, stream>>>(q16, k16, vt16, maskF, x16);
  gemm_out16<<<256, 512, 0, stream>>>(x16, wp16, bp, out);
}